// Round 1
// baseline (101.454 us; speedup 1.0000x reference)
//
#include <hip/hip_runtime.h>

#define NB 4
#define NP 160
#define NL 128
#define NH 768
#define NT 9

// ---------------- Kernel A: partial min over bert_embs -> ws[0..63] ----------------
__global__ void kmin_partial(const float* __restrict__ x, int n, float* __restrict__ part) {
    __shared__ float red[256];
    float m = 3.0e38f;
    for (int i = blockIdx.x * 256 + threadIdx.x; i < n; i += gridDim.x * 256)
        m = fminf(m, x[i]);
    red[threadIdx.x] = m;
    __syncthreads();
    for (int s = 128; s > 0; s >>= 1) {
        if (threadIdx.x < s) red[threadIdx.x] = fminf(red[threadIdx.x], red[threadIdx.x + s]);
        __syncthreads();
    }
    if (threadIdx.x == 0) part[blockIdx.x] = red[0];
}

// ---------------- Kernel B: detect bool storage (int32 vs 1-byte) ----------------
// Scan the first (B*L*P)/4 u32 words of pieces2word. If stored as int32 (0/1),
// every word is <=1. If stored as bytes, piece runs at arbitrary byte alignments
// guarantee some word >1. flag=1 -> int32, flag=0 -> bytes.
__global__ void kdetect(const unsigned* __restrict__ p, int n, int* __restrict__ flag) {
    __shared__ int anybad;
    if (threadIdx.x == 0) anybad = 0;
    __syncthreads();
    int bad = 0;
    for (int i = threadIdx.x; i < n; i += 256)
        if (p[i] > 1u) { bad = 1; break; }
    if (bad) anybad = 1;
    __syncthreads();
    if (threadIdx.x == 0) *flag = (anybad ? 0 : 1);
}

__device__ __forceinline__ int load_bool(const void* base, int idx, int is_int) {
    if (is_int) return ((const int*)base)[idx] != 0;
    return ((const unsigned char*)base)[idx] != 0;
}

// ---------------- Kernel C: word pooling + logits ----------------
// One block per (b, l). 256 threads.
__global__ void klogits(const float* __restrict__ embs, const void* __restrict__ p2w,
                        const void* __restrict__ masks, const float* __restrict__ W,
                        const float* __restrict__ bias, const float* __restrict__ part,
                        const int* __restrict__ flag, float* __restrict__ logits) {
    const int bl = blockIdx.x;           // 0..511
    const int b  = bl / NL;
    const int l  = bl % NL;
    const int tid = threadIdx.x;

    __shared__ float wrsh[NH];
    __shared__ int   plist[NP];
    __shared__ int   cnt;
    __shared__ float minv_sh;

    const int is_int = *flag;

    // reduce the 64 partial mins (wave 0)
    if (tid < 64) {
        float m = part[tid];
        #pragma unroll
        for (int o = 32; o > 0; o >>= 1) m = fminf(m, __shfl_down(m, o));
        if (tid == 0) { minv_sh = m; cnt = 0; }
    }
    __syncthreads();

    // build piece list for this word (order irrelevant for max)
    if (tid < NP) {
        if (load_bool(p2w, (b * NL + l) * NP + tid, is_int)) {
            int k = atomicAdd(&cnt, 1);
            plist[k] = tid;
        }
    }
    __syncthreads();

    const float minv = minv_sh;
    const int   nc   = cnt;
    const float mk   = load_bool(masks, b * NL + l, is_int) ? 1.0f : 0.0f;

    // word_reps: max over selected pieces (min_value if none), then * mask
    #pragma unroll
    for (int k = 0; k < 3; k++) {
        int h = tid + k * 256;
        float wr = minv;
        for (int i = 0; i < nc; i++)
            wr = fmaxf(wr, embs[(b * NP + plist[i]) * NH + h]);
        wrsh[h] = wr * mk;
    }
    __syncthreads();

    // logits[t] = sum_h wr[h] * W[h, t] + bias[t]; wave w handles t = w, w+4, ...
    const int w = tid >> 6, lane = tid & 63;
    for (int t = w; t < NT; t += 4) {
        float acc = 0.f;
        for (int h = lane; h < NH; h += 64)
            acc += wrsh[h] * W[h * NT + t];
        #pragma unroll
        for (int o = 32; o > 0; o >>= 1) acc += __shfl_down(acc, o);
        if (lane == 0) logits[bl * NT + t] = acc + bias[t];
    }
}

// ---------------- Kernel D: CRF log-likelihood + loss ----------------
// 1 block, 256 threads = 4 waves, one wave per batch. Lanes 0..8 hold alpha[c].
__global__ void kcrf(const float* __restrict__ logits, const int* __restrict__ labels,
                     const void* __restrict__ masks, const int* __restrict__ sent_length,
                     const float* __restrict__ start_t, const float* __restrict__ end_t,
                     const float* __restrict__ trans, const int* __restrict__ flag,
                     float* __restrict__ loss_out) {
    __shared__ float trs[NT * NT];
    __shared__ float llh[NB];
    const int tid = threadIdx.x;
    if (tid < NT * NT) trs[tid] = trans[tid];
    __syncthreads();

    const int is_int = *flag;
    const int b = tid >> 6;
    const int lane = tid & 63;
    const int c = (lane < NT) ? lane : 0;       // clamped tag index

    const float* em  = logits + b * NL * NT;
    const int*   lab = labels + b * NL;

    // alpha init + numerator init
    float a = start_t[c] + em[c];               // valid for lanes < NT
    float num = 0.f;
    if (lane == 0) {
        int t0 = lab[0];
        num = start_t[t0] + em[t0];
    }

    for (int i = 1; i < NL; i++) {
        // gather alpha from lanes 0..8 (all 64 lanes execute the shuffles)
        float ap[NT];
        #pragma unroll
        for (int p = 0; p < NT; p++) ap[p] = __shfl(a, p);

        float em_c = em[i * NT + c];
        float x0 = ap[0] + trs[0 * NT + c];
        float mx = x0;
        #pragma unroll
        for (int p = 1; p < NT; p++) mx = fmaxf(mx, ap[p] + trs[p * NT + c]);
        float s = 0.f;
        #pragma unroll
        for (int p = 0; p < NT; p++) s += __expf(ap[p] + trs[p * NT + c] - mx);
        float nxt = mx + __logf(s) + em_c;

        int m_i = load_bool(masks, b * NL + i, is_int);   // wave-uniform
        if (m_i) {
            if (lane < NT) a = nxt;
            if (lane == 0) num += trs[lab[i - 1] * NT + lab[i]] + em[i * NT + lab[i]];
        }
    }

    // denominator: logsumexp(alpha + end_t)
    float xv = a + end_t[c];
    float dv[NT];
    #pragma unroll
    for (int p = 0; p < NT; p++) dv[p] = __shfl(xv, p);

    if (lane == 0) {
        float mx = dv[0];
        #pragma unroll
        for (int p = 1; p < NT; p++) mx = fmaxf(mx, dv[p]);
        float s = 0.f;
        #pragma unroll
        for (int p = 0; p < NT; p++) s += __expf(dv[p] - mx);
        float den = mx + __logf(s);

        int last = sent_length[b] - 1;
        num += end_t[lab[last]];
        llh[b] = num - den;
    }
    __syncthreads();
    if (tid == 0) loss_out[0] = -(llh[0] + llh[1] + llh[2] + llh[3]);
}

extern "C" void kernel_launch(void* const* d_in, const int* in_sizes, int n_in,
                              void* d_out, int out_size, void* d_ws, size_t ws_size,
                              hipStream_t stream) {
    const float* embs    = (const float*)d_in[0];
    const void*  p2w     = d_in[1];
    const void*  masks   = d_in[2];
    const int*   labels  = (const int*)d_in[3];
    const int*   sentlen = (const int*)d_in[4];
    const float* W       = (const float*)d_in[5];
    const float* bias    = (const float*)d_in[6];
    const float* start_t = (const float*)d_in[7];
    const float* end_t   = (const float*)d_in[8];
    const float* trans   = (const float*)d_in[9];

    float* out = (float*)d_out;              // out[0] = loss, out[1..] = logits (B,L,T)
    float* part = (float*)d_ws;              // ws[0..63]: partial mins
    int*   flag = (int*)((char*)d_ws + 64 * sizeof(float));  // ws[64]: bool-dtype flag

    kmin_partial<<<64, 256, 0, stream>>>(embs, NB * NP * NH, part);
    kdetect<<<1, 256, 0, stream>>>((const unsigned*)p2w, (NB * NL * NP) / 4, flag);
    klogits<<<NB * NL, 256, 0, stream>>>(embs, p2w, masks, W, bias, part, flag, out + 1);
    kcrf<<<1, 256, 0, stream>>>(out + 1, labels, masks, sentlen, start_t, end_t, trans, flag, out);
}

// Round 2
// 51.457 us; speedup vs baseline: 1.9716x; 1.9716x over previous
//
#include <hip/hip_runtime.h>

#define NB 4
#define NP 160
#define NL 128
#define NH 768
#define NT 9
#define L2E 1.4426950408889634f
#define LN2 0.6931471805599453f

// ---------------- Kernel 1: fused partial-min (blocks 0..63) + bool-dtype detect (block 64) ----
// Detect: scan pieces2word as u32. int32-bool -> all words 0/1; byte-bool -> some word >1
// (piece runs of 1-2 trues at arbitrary byte alignments guarantee it). flag=1 -> int32.
__global__ void kprep(const float* __restrict__ x, int n,
                      const unsigned* __restrict__ p, int np,
                      float* __restrict__ part, int* __restrict__ flag) {
    if (blockIdx.x == 64) {
        __shared__ int anybad;
        if (threadIdx.x == 0) anybad = 0;
        __syncthreads();
        int bad = 0;
        for (int i = threadIdx.x; i < np; i += 256)
            if (p[i] > 1u) { bad = 1; break; }
        if (bad) anybad = 1;
        __syncthreads();
        if (threadIdx.x == 0) *flag = (anybad ? 0 : 1);
        return;
    }
    __shared__ float red[256];
    float m = 3.0e38f;
    for (int i = blockIdx.x * 256 + threadIdx.x; i < n; i += 64 * 256)
        m = fminf(m, x[i]);
    red[threadIdx.x] = m;
    __syncthreads();
    for (int s = 128; s > 0; s >>= 1) {
        if (threadIdx.x < s) red[threadIdx.x] = fminf(red[threadIdx.x], red[threadIdx.x + s]);
        __syncthreads();
    }
    if (threadIdx.x == 0) part[blockIdx.x] = red[0];
}

__device__ __forceinline__ int load_bool(const void* base, int idx, int is_int) {
    if (is_int) return ((const int*)base)[idx] != 0;
    return ((const unsigned char*)base)[idx] != 0;
}

// ---------------- Kernel 2: word pooling + logits. One block per (b, l). ----------------
__global__ void klogits(const float* __restrict__ embs, const void* __restrict__ p2w,
                        const void* __restrict__ masks, const float* __restrict__ W,
                        const float* __restrict__ bias, const float* __restrict__ part,
                        const int* __restrict__ flag, float* __restrict__ logits) {
    const int bl = blockIdx.x;           // 0..511
    const int b  = bl / NL;
    const int l  = bl % NL;
    const int tid = threadIdx.x;

    __shared__ float wrsh[NH];
    __shared__ int   plist[NP];
    __shared__ int   cnt;
    __shared__ float minv_sh;

    const int is_int = *flag;

    if (tid < 64) {
        float m = part[tid];
        #pragma unroll
        for (int o = 32; o > 0; o >>= 1) m = fminf(m, __shfl_down(m, o));
        if (tid == 0) { minv_sh = m; cnt = 0; }
    }
    __syncthreads();

    if (tid < NP) {
        if (load_bool(p2w, (b * NL + l) * NP + tid, is_int)) {
            int k = atomicAdd(&cnt, 1);
            plist[k] = tid;
        }
    }
    __syncthreads();

    const float minv = minv_sh;
    const int   nc   = cnt;
    const float mk   = load_bool(masks, b * NL + l, is_int) ? 1.0f : 0.0f;

    #pragma unroll
    for (int k = 0; k < 3; k++) {
        int h = tid + k * 256;
        float wr = minv;
        for (int i = 0; i < nc; i++)
            wr = fmaxf(wr, embs[(b * NP + plist[i]) * NH + h]);
        wrsh[h] = wr * mk;
    }
    __syncthreads();

    const int w = tid >> 6, lane = tid & 63;
    for (int t = w; t < NT; t += 4) {
        float acc = 0.f;
        for (int h = lane; h < NH; h += 64)
            acc += wrsh[h] * W[h * NT + t];
        #pragma unroll
        for (int o = 32; o > 0; o >>= 1) acc += __shfl_down(acc, o);
        if (lane == 0) logits[bl * NT + t] = acc + bias[t];
    }
}

// ---------------- Kernel 3: CRF log-likelihood + loss (log2-domain, LDS-staged) ----------
// 1 block, 4 waves, one wave per batch; lanes 0..8 hold alpha[tag].
__global__ void kcrf(const float* __restrict__ logits, const int* __restrict__ labels,
                     const int* __restrict__ sentlen,
                     const float* __restrict__ start_t, const float* __restrict__ end_t,
                     const float* __restrict__ trans, float* __restrict__ loss_out) {
    __shared__ float em_s[NB * NL * NT + 16];   // scaled by log2(e); +pad for prefetch overread
    __shared__ float trs[NT * NT];              // scaled
    __shared__ int   lab_s[NB * NL];
    __shared__ float llh[NB];

    const int tid = threadIdx.x;
    for (int i = tid; i < NB * NL * NT; i += 256) em_s[i] = logits[i] * L2E;
    for (int i = tid; i < NB * NL; i += 256)     lab_s[i] = labels[i];
    if (tid < NT * NT) trs[tid] = trans[tid] * L2E;
    __syncthreads();

    const int b    = tid >> 6;
    const int lane = tid & 63;
    const int c    = (lane < NT) ? lane : 0;    // clamped tag; lanes>=9 mirror lane 0
    const int len  = sentlen[b];                // masks == arange < sent_length
    const float* em  = em_s + b * NL * NT;
    const int*   lab = lab_s + b * NL;

    // ---- numerator: fully parallel over positions ----
    float nsum = 0.f;
    for (int i = 1 + lane; i < len; i += 64) {
        int tp = lab[i - 1], tc = lab[i];
        nsum += trs[tp * NT + tc] + em[i * NT + tc];
    }
    #pragma unroll
    for (int o = 32; o > 0; o >>= 1) nsum += __shfl_down(nsum, o);   // lane 0 has the sum

    // ---- alpha recursion (serial over len) ----
    float tcol[NT];
    #pragma unroll
    for (int p = 0; p < NT; p++) tcol[p] = trs[p * NT + c];

    float a    = start_t[c] * L2E + em[c];
    float em_c = em[NT + c];                    // prefetch i=1
    for (int i = 1; i < len; i++) {
        float em_nx = em[(i + 1) * NT + c];     // prefetch next (pad covers overread)
        float v[NT];
        #pragma unroll
        for (int p = 0; p < NT; p++) v[p] = __shfl(a, p) + tcol[p];
        float mx = fmaxf(fmaxf(fmaxf(v[0], v[1]), v[2]),
                         fmaxf(fmaxf(fmaxf(v[3], v[4]), v[5]),
                               fmaxf(fmaxf(v[6], v[7]), v[8])));
        float e[NT];
        #pragma unroll
        for (int p = 0; p < NT; p++) {
            float d = v[p] - mx;
            asm("v_exp_f32 %0, %1" : "=v"(e[p]) : "v"(d));
        }
        float s = (((e[0] + e[1]) + (e[2] + e[3])) + ((e[4] + e[5]) + (e[6] + e[7]))) + e[8];
        float lg;
        asm("v_log_f32 %0, %1" : "=v"(lg) : "v"(s));
        a = mx + lg + em_c;
        em_c = em_nx;
    }

    // ---- denominator + loss ----
    float xv = a + end_t[c] * L2E;
    float dv[NT];
    #pragma unroll
    for (int p = 0; p < NT; p++) dv[p] = __shfl(xv, p);

    if (lane == 0) {
        float mx = fmaxf(fmaxf(fmaxf(dv[0], dv[1]), dv[2]),
                         fmaxf(fmaxf(fmaxf(dv[3], dv[4]), dv[5]),
                               fmaxf(fmaxf(dv[6], dv[7]), dv[8])));
        float s = 0.f;
        #pragma unroll
        for (int p = 0; p < NT; p++) {
            float d = dv[p] - mx, ee;
            asm("v_exp_f32 %0, %1" : "=v"(ee) : "v"(d));
            s += ee;
        }
        float lg;
        asm("v_log_f32 %0, %1" : "=v"(lg) : "v"(s));
        float den = mx + lg;
        float num = nsum + start_t[lab[0]] * L2E + em[lab[0]]
                         + end_t[lab[len - 1]] * L2E;
        llh[b] = (num - den) * LN2;
    }
    __syncthreads();
    if (tid == 0) loss_out[0] = -(llh[0] + llh[1] + llh[2] + llh[3]);
}

extern "C" void kernel_launch(void* const* d_in, const int* in_sizes, int n_in,
                              void* d_out, int out_size, void* d_ws, size_t ws_size,
                              hipStream_t stream) {
    const float* embs    = (const float*)d_in[0];
    const void*  p2w     = d_in[1];
    const void*  masks   = d_in[2];
    const int*   labels  = (const int*)d_in[3];
    const int*   sentlen = (const int*)d_in[4];
    const float* W       = (const float*)d_in[5];
    const float* bias    = (const float*)d_in[6];
    const float* start_t = (const float*)d_in[7];
    const float* end_t   = (const float*)d_in[8];
    const float* trans   = (const float*)d_in[9];

    float* out  = (float*)d_out;             // out[0] = loss, out[1..] = logits (B,L,T)
    float* part = (float*)d_ws;              // ws[0..63]: partial mins
    int*   flag = (int*)((char*)d_ws + 64 * sizeof(float));

    kprep<<<65, 256, 0, stream>>>(embs, NB * NP * NH, (const unsigned*)p2w,
                                  (NB * NL * NP) / 4, part, flag);
    klogits<<<NB * NL, 256, 0, stream>>>(embs, p2w, masks, W, bias, part, flag, out + 1);
    kcrf<<<1, 256, 0, stream>>>(out + 1, labels, sentlen, start_t, end_t, trans, out);
}